// Round 2
// baseline (1163.811 us; speedup 1.0000x reference)
//
#include <hip/hip_runtime.h>

typedef __attribute__((ext_vector_type(8))) short short8;
typedef __attribute__((ext_vector_type(4))) float floatx4;

#define DIM 384
#define NHEAD 12
#define HDIM 32

__device__ __forceinline__ float bf2f(unsigned int u) {
    union { unsigned int i; float f; } x; x.i = (u & 0xffffu) << 16; return x.f;
}
__device__ __forceinline__ unsigned short f2bf(float f) {
    union { float f; unsigned int i; } x; x.f = f;
    return (unsigned short)((x.i + 0x7fffu + ((x.i >> 16) & 1u)) >> 16);
}

// natural row (b*3136 + l) -> windowed row (w*49 + n)
__device__ __forceinline__ int nat2win(int r) {
    int b = r / 3136; int l = r - b * 3136;
    int hh = l / 56, wc = l - hh * 56;
    int wh = hh / 7, nr = hh - wh * 7;
    int ww = wc / 7, nc = wc - ww * 7;
    return ((b << 6) + wh * 8 + ww) * 49 + nr * 7 + nc;
}
// windowed row -> natural row
__device__ __forceinline__ int win2nat(int r) {
    int w = r / 49; int n = r - w * 49;
    int b = w >> 6; int wi = w & 63;
    int wh = wi >> 3, ww = wi & 7;
    int hh = wh * 7 + n / 7, wc = ww * 7 + n % 7;
    return b * 3136 + hh * 56 + wc;
}

// dst (N x K row-major, bf16) = transpose of src (K rows x N cols fp32, leading dim ld)
__global__ void transpose_kernel(const float* __restrict__ src,
                                 unsigned short* __restrict__ dst,
                                 int K, int N, int ld) {
    int i = blockIdx.x * blockDim.x + threadIdx.x;
    if (i >= K * N) return;
    int n = i / K, k = i - n * K;
    dst[i] = f2bf(src[(size_t)k * ld + n]);
}

// LayerNorm over 384, fp32 in -> bf16 out; one wave per row.
__global__ __launch_bounds__(64) void ln_kernel(const float* __restrict__ x,
                                                const float* __restrict__ g,
                                                const float* __restrict__ b,
                                                unsigned short* __restrict__ out,
                                                int windowed) {
    int r = blockIdx.x;
    int lane = threadIdx.x;
    const float* row = x + (size_t)r * DIM;
    float v[6];
    float s = 0.f, ss = 0.f;
#pragma unroll
    for (int j = 0; j < 3; j++) {
        int c = lane + j * 64;  // float2 chunk index, 192 per row
        float2 f = *(const float2*)(row + 2 * c);
        v[2 * j] = f.x; v[2 * j + 1] = f.y;
        s += f.x + f.y; ss += f.x * f.x + f.y * f.y;
    }
#pragma unroll
    for (int m = 1; m < 64; m <<= 1) {
        s += __shfl_xor(s, m);
        ss += __shfl_xor(ss, m);
    }
    float mean = s * (1.f / DIM);
    float var = ss * (1.f / DIM) - mean * mean;
    float rstd = rsqrtf(var + 1e-5f);
    int orow = windowed ? nat2win(r) : r;
    unsigned short* op = out + (size_t)orow * DIM;
#pragma unroll
    for (int j = 0; j < 3; j++) {
        int c = lane + j * 64;
        float2 gg = *(const float2*)(g + 2 * c);
        float2 bb = *(const float2*)(b + 2 * c);
        float o0 = (v[2 * j] - mean) * rstd * gg.x + bb.x;
        float o1 = (v[2 * j + 1] - mean) * rstd * gg.y + bb.y;
        unsigned int w = ((unsigned int)f2bf(o1) << 16) | f2bf(o0);
        *(unsigned int*)(op + 2 * c) = w;
    }
}

// One wave per (window, head). q windowed bf16 (50176x384), kv fp32 (2,16,12,49,32)
__global__ __launch_bounds__(64) void attn_kernel(const unsigned short* __restrict__ q,
                                                  const float* __restrict__ kv,
                                                  const int* __restrict__ rel_index,
                                                  const float* __restrict__ bias_table,
                                                  unsigned short* __restrict__ o) {
    __shared__ float qs[49][32], ks[49][32], vs[49][32];
    __shared__ float S[49][52];
    int wh_ = blockIdx.x;
    int w = wh_ / NHEAD, h = wh_ - w * NHEAD;
    int b = w >> 6;
    int t = threadIdx.x;

    for (int idx = t; idx < 49 * 16; idx += 64) {
        int n = idx >> 4, dp = idx & 15;
        unsigned int u = *(const unsigned int*)(q + (size_t)(w * 49 + n) * DIM + h * HDIM + dp * 2);
        qs[n][2 * dp] = bf2f(u); qs[n][2 * dp + 1] = bf2f(u >> 16);
    }
    const float* kbase = kv + (size_t)(b * NHEAD + h) * 49 * 32;
    const float* vbase = kbase + (size_t)16 * NHEAD * 49 * 32;
    for (int idx = t; idx < 49 * 16; idx += 64) {
        int n = idx >> 4, dp = idx & 15;
        float2 fk = *(const float2*)(kbase + n * 32 + dp * 2);
        float2 fv = *(const float2*)(vbase + n * 32 + dp * 2);
        ks[n][2 * dp] = fk.x; ks[n][2 * dp + 1] = fk.y;
        vs[n][2 * dp] = fv.x; vs[n][2 * dp + 1] = fv.y;
    }
    __syncthreads();
    for (int idx = t; idx < 49 * 49; idx += 64) {
        int n = idx / 49, m = idx - n * 49;
        float sv = 0.f;
#pragma unroll
        for (int d = 0; d < 32; d++) sv += qs[n][d] * ks[m][d];
        sv += bias_table[rel_index[idx] * NHEAD + h];
        S[n][m] = sv;
    }
    __syncthreads();
    if (t < 49) {
        float mx = -1e30f;
        for (int m = 0; m < 49; m++) mx = fmaxf(mx, S[t][m]);
        float sum = 0.f;
        for (int m = 0; m < 49; m++) { float e = __expf(S[t][m] - mx); S[t][m] = e; sum += e; }
        float inv = 1.f / sum;
        for (int m = 0; m < 49; m++) S[t][m] *= inv;
    }
    __syncthreads();
    for (int idx = t; idx < 49 * 32; idx += 64) {
        int n = idx >> 5, d = idx & 31;
        float sv = 0.f;
        for (int m = 0; m < 49; m++) sv += S[n][m] * vs[m][d];
        o[(size_t)(w * 49 + n) * DIM + h * HDIM + d] = f2bf(sv);
    }
}

// C[M,N] = A[M,K](bf16) @ Bt[N,K](bf16)^T ; epilogue: +bias(fp32), optional GELU,
// *scale, optional fp32 residual at (possibly remapped) output row.
// OUT_BF16: out is bf16 buffer, else fp32.
template <int DO_GELU, int DO_REMAP, int OUT_BF16>
__global__ __launch_bounds__(256) void gemm_kernel(const unsigned short* __restrict__ A,
                                                   const unsigned short* __restrict__ Bt,
                                                   const float* __restrict__ bias,
                                                   const float* __restrict__ res,
                                                   void* __restrict__ outv,
                                                   int M, int N, int K, float scale) {
    __shared__ alignas(16) unsigned short As[128 * 32];
    __shared__ alignas(16) unsigned short Bs[128 * 32];
    int m0 = blockIdx.y * 128;
    int n0 = blockIdx.x * 128;
    int t = threadIdx.x;
    int lane = t & 63;
    int wv = t >> 6;
    int wm = (wv >> 1) * 64, wn = (wv & 1) * 64;
    int lr = lane & 15;
    int lq = lane >> 4;

    floatx4 acc[4][4];
#pragma unroll
    for (int i = 0; i < 4; i++)
#pragma unroll
        for (int j = 0; j < 4; j++) acc[i][j] = (floatx4)0.f;

    for (int k0 = 0; k0 < K; k0 += 32) {
#pragma unroll
        for (int cc = 0; cc < 2; cc++) {
            int c = t + cc * 256;
            int row = c >> 2, kc = (c & 3) * 8;
            *(uint4*)(&As[row * 32 + kc]) = *(const uint4*)(A + (size_t)(m0 + row) * K + k0 + kc);
            *(uint4*)(&Bs[row * 32 + kc]) = *(const uint4*)(Bt + (size_t)(n0 + row) * K + k0 + kc);
        }
        __syncthreads();
        short8 af[4], bfr[4];
#pragma unroll
        for (int i = 0; i < 4; i++) {
            af[i] = *(const short8*)(&As[(wm + i * 16 + lr) * 32 + lq * 8]);
            bfr[i] = *(const short8*)(&Bs[(wn + i * 16 + lr) * 32 + lq * 8]);
        }
#pragma unroll
        for (int i = 0; i < 4; i++)
#pragma unroll
            for (int j = 0; j < 4; j++)
                acc[i][j] = __builtin_amdgcn_mfma_f32_16x16x32_bf16(af[i], bfr[j], acc[i][j], 0, 0, 0);
        __syncthreads();
    }

#pragma unroll
    for (int j = 0; j < 4; j++) {
        int gcol = n0 + wn + j * 16 + lr;
        float bv = bias[gcol];
#pragma unroll
        for (int i = 0; i < 4; i++) {
#pragma unroll
            for (int r = 0; r < 4; r++) {
                int grow = m0 + wm + i * 16 + lq * 4 + r;
                float val = acc[i][j][r] + bv;
                if (DO_GELU) val = 0.5f * val * (1.f + erff(val * 0.70710678118654752f));
                val *= scale;
                int orow = DO_REMAP ? win2nat(grow) : grow;
                size_t idx = (size_t)orow * N + gcol;
                if (res) val += res[idx];
                if (OUT_BF16) ((unsigned short*)outv)[idx] = f2bf(val);
                else          ((float*)outv)[idx] = val;
            }
        }
    }
}

extern "C" void kernel_launch(void* const* d_in, const int* in_sizes, int n_in,
                              void* d_out, int out_size, void* d_ws, size_t ws_size,
                              hipStream_t stream) {
    const float* x          = (const float*)d_in[0];
    const float* kv         = (const float*)d_in[1];
    const int*   rel_index  = (const int*)d_in[2];
    const float* g1         = (const float*)d_in[5];
    const float* b1         = (const float*)d_in[6];
    const float* Wqkv       = (const float*)d_in[7];
    const float* bqkv       = (const float*)d_in[8];
    const float* bias_table = (const float*)d_in[9];
    const float* Wproj      = (const float*)d_in[10];
    const float* bproj      = (const float*)d_in[11];
    const float* g2         = (const float*)d_in[12];
    const float* b2         = (const float*)d_in[13];
    const float* Wfc1       = (const float*)d_in[14];
    const float* bfc1       = (const float*)d_in[15];
    const float* Wfc2       = (const float*)d_in[16];
    const float* bfc2       = (const float*)d_in[17];
    float* out = (float*)d_out;

    char* ws = (char*)d_ws;
    unsigned short* wq_t   = (unsigned short*)(ws);                    // 384x384 bf16
    unsigned short* wp_t   = (unsigned short*)(ws + 294912);           // 384x384
    unsigned short* wfc1_t = (unsigned short*)(ws + 589824);           // 1536x384
    unsigned short* wfc2_t = (unsigned short*)(ws + 1769472);          // 384x1536
    unsigned short* bufA   = (unsigned short*)(ws + 2949120);          // 50176x384 bf16
    unsigned short* bufB   = (unsigned short*)(ws + 2949120 + 38535168); // q, then MLP hidden

    const int M = 50176;
    const float scale = 0.17677669529663687f;  // 32^-0.5

    // Pre-transpose weights to (N x K) bf16 (q-part of Wqkv only)
    transpose_kernel<<<(384 * 384 + 255) / 256, 256, 0, stream>>>(Wqkv, wq_t, 384, 384, 1152);
    transpose_kernel<<<(384 * 384 + 255) / 256, 256, 0, stream>>>(Wproj, wp_t, 384, 384, 384);
    transpose_kernel<<<(384 * 1536 + 255) / 256, 256, 0, stream>>>(Wfc1, wfc1_t, 384, 1536, 1536);
    transpose_kernel<<<(1536 * 384 + 255) / 256, 256, 0, stream>>>(Wfc2, wfc2_t, 1536, 384, 384);

    // LN1 -> windowed layout (bf16)
    ln_kernel<<<M, 64, 0, stream>>>(x, g1, b1, bufA, 1);
    // q = (hw @ Wq + bq) * scale  -> bufB (bf16, windowed)
    gemm_kernel<0, 0, 1><<<dim3(3, 392), 256, 0, stream>>>(bufA, wq_t, bqkv, nullptr, bufB,
                                                           M, 384, 384, scale);
    // windowed attention -> bufA (bf16, windowed)
    attn_kernel<<<1024 * NHEAD, 64, 0, stream>>>(bufB, kv, rel_index, bias_table, bufA);
    // proj + window_reverse + residual(x, fp32) -> d_out (fp32, natural)
    gemm_kernel<0, 1, 0><<<dim3(3, 392), 256, 0, stream>>>(bufA, wp_t, bproj, x, d_out,
                                                           M, 384, 384, 1.f);
    // LN2: d_out -> bufA (bf16)
    ln_kernel<<<M, 64, 0, stream>>>(out, g2, b2, bufA, 0);
    // MLP in 4 row-chunks of 12544 (=98*128); hidden aliases bufB
    for (int c = 0; c < 4; c++) {
        size_t ro = (size_t)c * 12544;
        gemm_kernel<1, 0, 1><<<dim3(12, 98), 256, 0, stream>>>(bufA + ro * 384, wfc1_t, bfc1,
                                                               nullptr, bufB, 12544, 1536, 384, 1.f);
        gemm_kernel<0, 0, 0><<<dim3(3, 98), 256, 0, stream>>>(bufB, wfc2_t, bfc2,
                                                              out + ro * 384, out + ro * 384,
                                                              12544, 384, 1536, 1.f);
    }
}

// Round 3
// 915.051 us; speedup vs baseline: 1.2719x; 1.2719x over previous
//
#include <hip/hip_runtime.h>

typedef __attribute__((ext_vector_type(8))) short short8;
typedef __attribute__((ext_vector_type(4))) float floatx4;
typedef unsigned int u32;

#define DIM 384
#define NHEAD 12
#define HDIM 32

__device__ __forceinline__ float bf2f(unsigned int u) {
    union { unsigned int i; float f; } x; x.i = (u & 0xffffu) << 16; return x.f;
}
__device__ __forceinline__ unsigned short f2bf(float f) {
    union { float f; unsigned int i; } x; x.f = f;
    return (unsigned short)((x.i + 0x7fffu + ((x.i >> 16) & 1u)) >> 16);
}

__device__ __forceinline__ int nat2win(int r) {
    int b = r / 3136; int l = r - b * 3136;
    int hh = l / 56, wc = l - hh * 56;
    int wh = hh / 7, nr = hh - wh * 7;
    int ww = wc / 7, nc = wc - ww * 7;
    return ((b << 6) + wh * 8 + ww) * 49 + nr * 7 + nc;
}
__device__ __forceinline__ int win2nat(int r) {
    int w = r / 49; int n = r - w * 49;
    int b = w >> 6; int wi = w & 63;
    int wh = wi >> 3, ww = wi & 7;
    int hh = wh * 7 + n / 7, wc = ww * 7 + n % 7;
    return b * 3136 + hh * 56 + wc;
}

#define GLOAD_LDS16(g, l) \
    __builtin_amdgcn_global_load_lds((const __attribute__((address_space(1))) u32*)(g), \
                                     (__attribute__((address_space(3))) u32*)(l), 16, 0, 0)

// dst (N x K row-major, bf16) = transpose of src (K rows x N cols fp32, ld)
__global__ void transpose_kernel(const float* __restrict__ src,
                                 unsigned short* __restrict__ dst,
                                 int K, int N, int ld) {
    int i = blockIdx.x * blockDim.x + threadIdx.x;
    if (i >= K * N) return;
    int n = i / K, k = i - n * K;
    dst[i] = f2bf(src[(size_t)k * ld + n]);
}

// biasx[h][q*49+k] = bias_table[rel_index[q*49+k]*12 + h]
__global__ void bias_expand_kernel(const int* __restrict__ rel_index,
                                   const float* __restrict__ bias_table,
                                   float* __restrict__ biasx) {
    int i = blockIdx.x * blockDim.x + threadIdx.x;
    if (i >= NHEAD * 49 * 49) return;
    int h = i / 2401, r = i - h * 2401;
    biasx[i] = bias_table[rel_index[r] * NHEAD + h];
}

// LayerNorm over 384, fp32 in -> bf16 out; one wave per row.
__global__ __launch_bounds__(64) void ln_kernel(const float* __restrict__ x,
                                                const float* __restrict__ g,
                                                const float* __restrict__ b,
                                                unsigned short* __restrict__ out,
                                                int windowed) {
    int r = blockIdx.x;
    int lane = threadIdx.x;
    const float* row = x + (size_t)r * DIM;
    float v[6];
    float s = 0.f, ss = 0.f;
#pragma unroll
    for (int j = 0; j < 3; j++) {
        int c = lane + j * 64;
        float2 f = *(const float2*)(row + 2 * c);
        v[2 * j] = f.x; v[2 * j + 1] = f.y;
        s += f.x + f.y; ss += f.x * f.x + f.y * f.y;
    }
#pragma unroll
    for (int m = 1; m < 64; m <<= 1) {
        s += __shfl_xor(s, m);
        ss += __shfl_xor(ss, m);
    }
    float mean = s * (1.f / DIM);
    float var = ss * (1.f / DIM) - mean * mean;
    float rstd = rsqrtf(var + 1e-5f);
    int orow = windowed ? nat2win(r) : r;
    unsigned short* op = out + (size_t)orow * DIM;
#pragma unroll
    for (int j = 0; j < 3; j++) {
        int c = lane + j * 64;
        float2 gg = *(const float2*)(g + 2 * c);
        float2 bb = *(const float2*)(b + 2 * c);
        float o0 = (v[2 * j] - mean) * rstd * gg.x + bb.x;
        float o1 = (v[2 * j + 1] - mean) * rstd * gg.y + bb.y;
        unsigned int w = ((unsigned int)f2bf(o1) << 16) | f2bf(o0);
        *(unsigned int*)(op + 2 * c) = w;
    }
}

// MFMA window attention. 1 block = 1 window, 2 waves x 6 heads each.
// q windowed bf16 (50176x384); kv fp32 (2,16,12,49,32); biasx fp32 (12,49,49).
__global__ __launch_bounds__(128) void attn_kernel(const unsigned short* __restrict__ q,
                                                   const float* __restrict__ kv,
                                                   const float* __restrict__ biasx,
                                                   unsigned short* __restrict__ o) {
    __shared__ alignas(16) unsigned short Qs[2][64 * 32];
    __shared__ alignas(16) unsigned short Ks[2][64 * 32];
    __shared__ alignas(16) unsigned short Vt[2][32 * 72];
    __shared__ alignas(16) unsigned short Ps[2][64 * 72];

    int w = blockIdx.x;
    int b = w >> 6;
    int t = threadIdx.x;
    int lane = t & 63;
    int u = t >> 6;
    int lr = lane & 15;   // col within 16-tile / A-row
    int lg = lane >> 4;   // row-group / k-chunk
    // one-time zero padding: Q/K rows 49..63, Vt cols 48..71
    for (int idx = lane; idx < 15 * 16; idx += 64) {
        int r = 49 + (idx >> 4), c2 = idx & 15;
        *(u32*)&Qs[u][r * 32 + c2 * 2] = 0;
        *(u32*)&Ks[u][r * 32 + c2 * 2] = 0;
    }
    for (int idx = lane; idx < 32 * 12; idx += 64) {
        int d = idx / 12, c2 = idx - d * 12;
        *(u32*)&Vt[u][d * 72 + 48 + c2 * 2] = 0;
    }

    for (int hi = 0; hi < 6; hi++) {
        int h = u * 6 + hi;
        // ---- stage Q (bf16 global -> LDS) ----
#pragma unroll
        for (int it = 0; it < 4; it++) {
            int idx = lane + it * 64;          // 256 = 64 rows x 4 parts
            int row = idx >> 2, part = idx & 3;
            if (row < 49) {
                uint4 val = *(const uint4*)(q + ((size_t)(w * 49 + row)) * DIM + h * 32 + part * 8);
                *(uint4*)&Qs[u][row * 32 + part * 8] = val;
            }
        }
        // ---- stage K (fp32 -> bf16 LDS) ----
        const float* kptr = kv + (size_t)(b * NHEAD + h) * 1568;
#pragma unroll
        for (int it = 0; it < 7; it++) {
            int idx = lane + it * 64;          // 392 = 49 rows x 8 segs
            if (idx < 392) {
                int row = idx >> 3, seg = idx & 7;
                float4 f = *(const float4*)(kptr + row * 32 + seg * 4);
                ushort4 h4; h4.x = f2bf(f.x); h4.y = f2bf(f.y); h4.z = f2bf(f.z); h4.w = f2bf(f.w);
                *(ushort4*)&Ks[u][row * 32 + seg * 4] = h4;
            }
        }
        // ---- stage V transposed (fp32 -> bf16 LDS Vt[d][m]) ----
        const float* vptr = kv + (size_t)(192 + b * NHEAD + h) * 1568;
#pragma unroll
        for (int it = 0; it < 13; it++) {
            int idx = lane + it * 64;          // 784 = 49 rows x 16 dpairs
            if (idx < 784) {
                int m = idx >> 4, dp = idx & 15;
                float2 f = *(const float2*)(vptr + m * 32 + dp * 2);
                Vt[u][(2 * dp) * 72 + m]     = f2bf(f.x);
                Vt[u][(2 * dp + 1) * 72 + m] = f2bf(f.y);
            }
        }
        __syncthreads();

        // ---- S = Q @ K^T : 4x4 tiles of 16x16, K=32 ----
        floatx4 sfrag[4][4];
#pragma unroll
        for (int mi = 0; mi < 4; mi++)
#pragma unroll
            for (int ni = 0; ni < 4; ni++) sfrag[mi][ni] = (floatx4)0.f;
        short8 af[4], bfr[4];
#pragma unroll
        for (int mi = 0; mi < 4; mi++) af[mi] = *(const short8*)&Qs[u][(mi * 16 + lr) * 32 + lg * 8];
#pragma unroll
        for (int ni = 0; ni < 4; ni++) bfr[ni] = *(const short8*)&Ks[u][(ni * 16 + lr) * 32 + lg * 8];
#pragma unroll
        for (int mi = 0; mi < 4; mi++)
#pragma unroll
            for (int ni = 0; ni < 4; ni++)
                sfrag[mi][ni] = __builtin_amdgcn_mfma_f32_16x16x32_bf16(af[mi], bfr[ni], sfrag[mi][ni], 0, 0, 0);

        // ---- bias + masked softmax in registers, write P (bf16) to LDS ----
        const float* bh = biasx + h * 2401;
#pragma unroll
        for (int mi = 0; mi < 4; mi++) {
#pragma unroll
            for (int reg = 0; reg < 4; reg++) {
                int qr = mi * 16 + lg * 4 + reg;
                float mx = -1e30f;
#pragma unroll
                for (int ni = 0; ni < 4; ni++) {
                    int k = ni * 16 + lr;
                    float s = sfrag[mi][ni][reg];
                    if (k < 49) { if (qr < 49) s += bh[qr * 49 + k]; }
                    else s = -1e30f;
                    sfrag[mi][ni][reg] = s;
                    mx = fmaxf(mx, s);
                }
#pragma unroll
                for (int j = 1; j < 16; j <<= 1) mx = fmaxf(mx, __shfl_xor(mx, j));
                float sum = 0.f;
#pragma unroll
                for (int ni = 0; ni < 4; ni++) {
                    float e = __expf(sfrag[mi][ni][reg] - mx);
                    sfrag[mi][ni][reg] = e;
                    sum += e;
                }
#pragma unroll
                for (int j = 1; j < 16; j <<= 1) sum += __shfl_xor(sum, j);
                float inv = 1.f / sum;
                if (qr < 49) {
#pragma unroll
                    for (int ni = 0; ni < 4; ni++)
                        Ps[u][qr * 72 + ni * 16 + lr] = f2bf(sfrag[mi][ni][reg] * inv);
                }
            }
        }
        __syncthreads();

        // ---- O = P @ V : K-dim 64 (2 steps), N-dim 32 (2 tiles) ----
        floatx4 ofrag[4][2];
#pragma unroll
        for (int mi = 0; mi < 4; mi++) { ofrag[mi][0] = (floatx4)0.f; ofrag[mi][1] = (floatx4)0.f; }
#pragma unroll
        for (int ks = 0; ks < 2; ks++) {
            short8 paf[4], vbf[2];
#pragma unroll
            for (int mi = 0; mi < 4; mi++)
                paf[mi] = *(const short8*)&Ps[u][(mi * 16 + lr) * 72 + ks * 32 + lg * 8];
#pragma unroll
            for (int ni = 0; ni < 2; ni++)
                vbf[ni] = *(const short8*)&Vt[u][(ni * 16 + lr) * 72 + ks * 32 + lg * 8];
#pragma unroll
            for (int mi = 0; mi < 4; mi++)
#pragma unroll
                for (int ni = 0; ni < 2; ni++)
                    ofrag[mi][ni] = __builtin_amdgcn_mfma_f32_16x16x32_bf16(paf[mi], vbf[ni], ofrag[mi][ni], 0, 0, 0);
        }
        // ---- write O ----
#pragma unroll
        for (int mi = 0; mi < 4; mi++) {
#pragma unroll
            for (int reg = 0; reg < 4; reg++) {
                int qr = mi * 16 + lg * 4 + reg;
                if (qr < 49) {
#pragma unroll
                    for (int ni = 0; ni < 2; ni++)
                        o[((size_t)(w * 49 + qr)) * DIM + h * 32 + ni * 16 + lr] = f2bf(ofrag[mi][ni][reg]);
                }
            }
        }
        __syncthreads();
    }
}

// C[M,N] = A[M,K](bf16) @ Bt[N,K](bf16)^T ; +bias, opt GELU, *scale, opt fp32 residual.
template <int DO_GELU, int DO_REMAP, int OUT_BF16>
__global__ __launch_bounds__(256) void gemm_kernel(const unsigned short* __restrict__ A,
                                                   const unsigned short* __restrict__ Bt,
                                                   const float* __restrict__ bias,
                                                   const float* __restrict__ res,
                                                   void* __restrict__ outv,
                                                   int M, int N, int K, float scale) {
    __shared__ alignas(16) unsigned short As[128 * 32];
    __shared__ alignas(16) unsigned short Bs[128 * 32];
    int m0 = blockIdx.y * 128;
    int n0 = blockIdx.x * 128;
    int t = threadIdx.x;
    int lane = t & 63;
    int wv = t >> 6;
    int wm = (wv >> 1) * 64, wn = (wv & 1) * 64;
    int lr = lane & 15;
    int lq = lane >> 4;

    floatx4 acc[4][4];
#pragma unroll
    for (int i = 0; i < 4; i++)
#pragma unroll
        for (int j = 0; j < 4; j++) acc[i][j] = (floatx4)0.f;

    for (int k0 = 0; k0 < K; k0 += 32) {
#pragma unroll
        for (int cc = 0; cc < 2; cc++) {
            int c = t + cc * 256;
            int row = c >> 2, kc = (c & 3) * 8;
            GLOAD_LDS16(A + (size_t)(m0 + row) * K + k0 + kc, &As[row * 32 + kc]);
            GLOAD_LDS16(Bt + (size_t)(n0 + row) * K + k0 + kc, &Bs[row * 32 + kc]);
        }
        __syncthreads();
        short8 af[4], bfr[4];
#pragma unroll
        for (int i = 0; i < 4; i++) {
            af[i] = *(const short8*)(&As[(wm + i * 16 + lr) * 32 + lq * 8]);
            bfr[i] = *(const short8*)(&Bs[(wn + i * 16 + lr) * 32 + lq * 8]);
        }
#pragma unroll
        for (int i = 0; i < 4; i++)
#pragma unroll
            for (int j = 0; j < 4; j++)
                acc[i][j] = __builtin_amdgcn_mfma_f32_16x16x32_bf16(af[i], bfr[j], acc[i][j], 0, 0, 0);
        __syncthreads();
    }

#pragma unroll
    for (int j = 0; j < 4; j++) {
        int gcol = n0 + wn + j * 16 + lr;
        float bv = bias[gcol];
#pragma unroll
        for (int i = 0; i < 4; i++) {
#pragma unroll
            for (int r = 0; r < 4; r++) {
                int grow = m0 + wm + i * 16 + lq * 4 + r;
                float val = acc[i][j][r] + bv;
                if (DO_GELU) val = 0.5f * val * (1.f + erff(val * 0.70710678118654752f));
                val *= scale;
                int orow = DO_REMAP ? win2nat(grow) : grow;
                size_t idx = (size_t)orow * N + gcol;
                if (res) val += res[idx];
                if (OUT_BF16) ((unsigned short*)outv)[idx] = f2bf(val);
                else          ((float*)outv)[idx] = val;
            }
        }
    }
}

extern "C" void kernel_launch(void* const* d_in, const int* in_sizes, int n_in,
                              void* d_out, int out_size, void* d_ws, size_t ws_size,
                              hipStream_t stream) {
    const float* x          = (const float*)d_in[0];
    const float* kv         = (const float*)d_in[1];
    const int*   rel_index  = (const int*)d_in[2];
    const float* g1         = (const float*)d_in[5];
    const float* b1         = (const float*)d_in[6];
    const float* Wqkv       = (const float*)d_in[7];
    const float* bqkv       = (const float*)d_in[8];
    const float* bias_table = (const float*)d_in[9];
    const float* Wproj      = (const float*)d_in[10];
    const float* bproj      = (const float*)d_in[11];
    const float* g2         = (const float*)d_in[12];
    const float* b2         = (const float*)d_in[13];
    const float* Wfc1       = (const float*)d_in[14];
    const float* bfc1       = (const float*)d_in[15];
    const float* Wfc2       = (const float*)d_in[16];
    const float* bfc2       = (const float*)d_in[17];
    float* out = (float*)d_out;

    char* ws = (char*)d_ws;
    unsigned short* wq_t   = (unsigned short*)(ws);                    // 384x384 bf16
    unsigned short* wp_t   = (unsigned short*)(ws + 294912);
    unsigned short* wfc1_t = (unsigned short*)(ws + 589824);           // 1536x384
    unsigned short* wfc2_t = (unsigned short*)(ws + 1769472);          // 384x1536
    float*          biasx  = (float*)(ws + 2949120);                   // 12x49x49 fp32
    unsigned short* bufA   = (unsigned short*)(ws + 3080192);          // 50176x384 bf16
    unsigned short* bufB   = (unsigned short*)(ws + 3080192 + 38535168);

    const int M = 50176;
    const float scale = 0.17677669529663687f;  // 32^-0.5

    transpose_kernel<<<(384 * 384 + 255) / 256, 256, 0, stream>>>(Wqkv, wq_t, 384, 384, 1152);
    transpose_kernel<<<(384 * 384 + 255) / 256, 256, 0, stream>>>(Wproj, wp_t, 384, 384, 384);
    transpose_kernel<<<(384 * 1536 + 255) / 256, 256, 0, stream>>>(Wfc1, wfc1_t, 384, 1536, 1536);
    transpose_kernel<<<(1536 * 384 + 255) / 256, 256, 0, stream>>>(Wfc2, wfc2_t, 1536, 384, 384);
    bias_expand_kernel<<<(NHEAD * 2401 + 255) / 256, 256, 0, stream>>>(rel_index, bias_table, biasx);

    // LN1 -> windowed (bf16)
    ln_kernel<<<M, 64, 0, stream>>>(x, g1, b1, bufA, 1);
    // q = (hw @ Wq + bq) * scale -> bufB
    gemm_kernel<0, 0, 1><<<dim3(3, 392), 256, 0, stream>>>(bufA, wq_t, bqkv, nullptr, bufB,
                                                           M, 384, 384, scale);
    // MFMA attention -> bufA
    attn_kernel<<<1024, 128, 0, stream>>>(bufB, kv, biasx, bufA);
    // proj + window_reverse + residual(x) -> d_out (fp32)
    gemm_kernel<0, 1, 0><<<dim3(3, 392), 256, 0, stream>>>(bufA, wp_t, bproj, x, d_out,
                                                           M, 384, 384, 1.f);
    // LN2
    ln_kernel<<<M, 64, 0, stream>>>(out, g2, b2, bufA, 0);
    // MLP in 4 chunks; hidden aliases bufB
    for (int c = 0; c < 4; c++) {
        size_t ro = (size_t)c * 12544;
        gemm_kernel<1, 0, 1><<<dim3(12, 98), 256, 0, stream>>>(bufA + ro * 384, wfc1_t, bfc1,
                                                               nullptr, bufB, 12544, 1536, 384, 1.f);
        gemm_kernel<0, 0, 0><<<dim3(3, 98), 256, 0, stream>>>(bufB, wfc2_t, bfc2,
                                                              out + ro * 384, out + ro * 384,
                                                              12544, 384, 1536, 1.f);
    }
}

// Round 4
// 696.008 us; speedup vs baseline: 1.6721x; 1.3147x over previous
//
#include <hip/hip_runtime.h>

typedef __attribute__((ext_vector_type(8))) short short8;
typedef __attribute__((ext_vector_type(4))) float floatx4;
typedef unsigned int u32;

#define DIM 384
#define NHEAD 12
#define HDIM 32

__device__ __forceinline__ float bf2f(unsigned int u) {
    union { unsigned int i; float f; } x; x.i = (u & 0xffffu) << 16; return x.f;
}
__device__ __forceinline__ unsigned short f2bf(float f) {
    union { float f; unsigned int i; } x; x.f = f;
    return (unsigned short)((x.i + 0x7fffu + ((x.i >> 16) & 1u)) >> 16);
}

__device__ __forceinline__ int nat2win(int r) {
    int b = r / 3136; int l = r - b * 3136;
    int hh = l / 56, wc = l - hh * 56;
    int wh = hh / 7, nr = hh - wh * 7;
    int ww = wc / 7, nc = wc - ww * 7;
    return ((b << 6) + wh * 8 + ww) * 49 + nr * 7 + nc;
}
__device__ __forceinline__ int win2nat(int r) {
    int w = r / 49; int n = r - w * 49;
    int b = w >> 6; int wi = w & 63;
    int wh = wi >> 3, ww = wi & 7;
    int hh = wh * 7 + n / 7, wc = ww * 7 + n % 7;
    return b * 3136 + hh * 56 + wc;
}

#define GLOAD_LDS16(g, l) \
    __builtin_amdgcn_global_load_lds((const __attribute__((address_space(1))) u32*)(g), \
                                     (__attribute__((address_space(3))) u32*)(l), 16, 0, 0)

__global__ void transpose_kernel(const float* __restrict__ src,
                                 unsigned short* __restrict__ dst,
                                 int K, int N, int ld) {
    int i = blockIdx.x * blockDim.x + threadIdx.x;
    if (i >= K * N) return;
    int n = i / K, k = i - n * K;
    dst[i] = f2bf(src[(size_t)k * ld + n]);
}

__global__ void bias_expand_kernel(const int* __restrict__ rel_index,
                                   const float* __restrict__ bias_table,
                                   float* __restrict__ biasx) {
    int i = blockIdx.x * blockDim.x + threadIdx.x;
    if (i >= NHEAD * 49 * 49) return;
    int h = i / 2401, r = i - h * 2401;
    biasx[i] = bias_table[rel_index[r] * NHEAD + h];
}

// LayerNorm over 384, fp32 in -> bf16 out; one wave per row.
__global__ __launch_bounds__(64) void ln_kernel(const float* __restrict__ x,
                                                const float* __restrict__ g,
                                                const float* __restrict__ b,
                                                unsigned short* __restrict__ out,
                                                int windowed) {
    int r = blockIdx.x;
    int lane = threadIdx.x;
    const float* row = x + (size_t)r * DIM;
    float v[6];
    float s = 0.f, ss = 0.f;
#pragma unroll
    for (int j = 0; j < 3; j++) {
        int c = lane + j * 64;
        float2 f = *(const float2*)(row + 2 * c);
        v[2 * j] = f.x; v[2 * j + 1] = f.y;
        s += f.x + f.y; ss += f.x * f.x + f.y * f.y;
    }
#pragma unroll
    for (int m = 1; m < 64; m <<= 1) {
        s += __shfl_xor(s, m);
        ss += __shfl_xor(ss, m);
    }
    float mean = s * (1.f / DIM);
    float var = ss * (1.f / DIM) - mean * mean;
    float rstd = rsqrtf(var + 1e-5f);
    int orow = windowed ? nat2win(r) : r;
    unsigned short* op = out + (size_t)orow * DIM;
#pragma unroll
    for (int j = 0; j < 3; j++) {
        int c = lane + j * 64;
        float2 gg = *(const float2*)(g + 2 * c);
        float2 bb = *(const float2*)(b + 2 * c);
        float o0 = (v[2 * j] - mean) * rstd * gg.x + bb.x;
        float o1 = (v[2 * j + 1] - mean) * rstd * gg.y + bb.y;
        unsigned int w = ((unsigned int)f2bf(o1) << 16) | f2bf(o0);
        *(unsigned int*)(op + 2 * c) = w;
    }
}

// MFMA attention: block = (image b, head h, group of 16 windows).
// 784 rows = 49 exact 16-row M-tiles, distributed over 4 waves.
// q windowed bf16 (50176x384); kv fp32 (2,16,12,49,32); biasx fp32 (12,49,49).
__global__ __launch_bounds__(256) void attn_kernel(const unsigned short* __restrict__ q,
                                                   const float* __restrict__ kv,
                                                   const float* __restrict__ biasx,
                                                   unsigned short* __restrict__ o) {
    __shared__ alignas(16) unsigned short Ks[64 * 40];   // [token][d] stride 40
    __shared__ alignas(16) unsigned short Vt[32 * 72];   // [d][token] stride 72
    __shared__ float Bi[49 * 52];                        // [qr][k] stride 52
    __shared__ alignas(16) unsigned short Ps[4][16 * 72];// per-wave P tile

    int blk = blockIdx.x;
    int b = blk / 48; int rem = blk - b * 48;
    int h = rem >> 2; int g = rem & 3;
    size_t row_base = (size_t)(b * 64 + g * 16) * 49;

    int t = threadIdx.x;
    int lane = t & 63;
    int wv = t >> 6;
    int lr = lane & 15;
    int lg = lane >> 4;

    // ---- stage K (fp32 -> bf16), Vt transposed, bias ----
    const float* kptr = kv + (size_t)(b * NHEAD + h) * 1568;
    for (int idx = t; idx < 392; idx += 256) {
        int row = idx >> 3, seg = idx & 7;
        float4 f = *(const float4*)(kptr + row * 32 + seg * 4);
        ushort4 h4; h4.x = f2bf(f.x); h4.y = f2bf(f.y); h4.z = f2bf(f.z); h4.w = f2bf(f.w);
        *(ushort4*)&Ks[row * 40 + seg * 4] = h4;
    }
    const float* vptr = kv + (size_t)(192 + b * NHEAD + h) * 1568;
    for (int idx = t; idx < 784; idx += 256) {
        int m = idx >> 4, dp = idx & 15;
        float2 f = *(const float2*)(vptr + m * 32 + dp * 2);
        Vt[(2 * dp) * 72 + m]     = f2bf(f.x);
        Vt[(2 * dp + 1) * 72 + m] = f2bf(f.y);
    }
    for (int idx = t; idx < 32 * 23; idx += 256) {      // zero Vt token-pad 49..71
        int d = idx / 23, m = 49 + idx - d * 23;
        Vt[d * 72 + m] = 0;
    }
    const float* bh = biasx + h * 2401;
    for (int idx = t; idx < 2401; idx += 256) {
        int qr = idx / 49, k = idx - qr * 49;
        Bi[qr * 52 + k] = bh[idx];
    }
    __syncthreads();

    // ---- shared fragments (loop-invariant) ----
    short8 bfr[4], vbf[2][2];
#pragma unroll
    for (int ni = 0; ni < 4; ni++)
        bfr[ni] = *(const short8*)&Ks[(ni * 16 + lr) * 40 + lg * 8];
#pragma unroll
    for (int ni = 0; ni < 2; ni++)
#pragma unroll
        for (int ks = 0; ks < 2; ks++)
            vbf[ni][ks] = *(const short8*)&Vt[(ni * 16 + lr) * 72 + ks * 32 + lg * 8];

    const unsigned short* qb = q + row_base * DIM + h * 32 + lg * 8;
    unsigned short* ob = o + row_base * DIM + h * 32;

    short8 af = *(const short8*)(qb + (size_t)(wv * 16 + lr) * DIM);
    for (int tm = wv; tm < 49; tm += 4) {
        short8 af_next;
        if (tm + 4 < 49) af_next = *(const short8*)(qb + (size_t)((tm + 4) * 16 + lr) * DIM);

        floatx4 sfrag[4];
#pragma unroll
        for (int ni = 0; ni < 4; ni++)
            sfrag[ni] = __builtin_amdgcn_mfma_f32_16x16x32_bf16(af, bfr[ni], (floatx4)0.f, 0, 0, 0);

        // bias + softmax (rows all valid; cols >=49 masked)
#pragma unroll
        for (int reg = 0; reg < 4; reg++) {
            int r_loc = tm * 16 + lg * 4 + reg;
            int qr = r_loc % 49;
            float mx = -1e30f;
#pragma unroll
            for (int ni = 0; ni < 4; ni++) {
                int k = ni * 16 + lr;
                float s = sfrag[ni][reg];
                if (k < 49) s += Bi[qr * 52 + k];
                else s = -1e30f;
                sfrag[ni][reg] = s;
                mx = fmaxf(mx, s);
            }
#pragma unroll
            for (int j = 1; j < 16; j <<= 1) mx = fmaxf(mx, __shfl_xor(mx, j));
            float sum = 0.f;
#pragma unroll
            for (int ni = 0; ni < 4; ni++) {
                float e = __expf(sfrag[ni][reg] - mx);
                sfrag[ni][reg] = e;
                sum += e;
            }
#pragma unroll
            for (int j = 1; j < 16; j <<= 1) sum += __shfl_xor(sum, j);
            float inv = 1.f / sum;
#pragma unroll
            for (int ni = 0; ni < 4; ni++)
                Ps[wv][(lg * 4 + reg) * 72 + ni * 16 + lr] = f2bf(sfrag[ni][reg] * inv);
        }
        // same-wave LDS round-trip (no barrier needed)
        floatx4 ofrag[2] = {(floatx4)0.f, (floatx4)0.f};
#pragma unroll
        for (int ks = 0; ks < 2; ks++) {
            short8 paf = *(const short8*)&Ps[wv][lr * 72 + ks * 32 + lg * 8];
#pragma unroll
            for (int ni = 0; ni < 2; ni++)
                ofrag[ni] = __builtin_amdgcn_mfma_f32_16x16x32_bf16(paf, vbf[ni][ks], ofrag[ni], 0, 0, 0);
        }
#pragma unroll
        for (int reg = 0; reg < 4; reg++) {
            size_t rg = (size_t)(tm * 16 + lg * 4 + reg) * DIM;
#pragma unroll
            for (int ni = 0; ni < 2; ni++)
                ob[rg + ni * 16 + lr] = f2bf(ofrag[ni][reg]);
        }
        af = af_next;
    }
}

// C[M,N] = A[M,K](bf16) @ Bt[N,K](bf16)^T ; BK=64, XOR-swizzled LDS.
template <int DO_GELU, int DO_REMAP, int OUT_BF16>
__global__ __launch_bounds__(256) void gemm_kernel(const unsigned short* __restrict__ A,
                                                   const unsigned short* __restrict__ Bt,
                                                   const float* __restrict__ bias,
                                                   const float* __restrict__ res,
                                                   void* __restrict__ outv,
                                                   int M, int N, int K, float scale) {
    __shared__ alignas(16) unsigned short As[128 * 64];
    __shared__ alignas(16) unsigned short Bs[128 * 64];
    int m0 = blockIdx.y * 128;
    int n0 = blockIdx.x * 128;
    int t = threadIdx.x;
    int lane = t & 63;
    int wv = t >> 6;
    int wm = (wv >> 1) * 64, wn = (wv & 1) * 64;
    int lr = lane & 15;
    int lq = lane >> 4;

    // staging maps: slot s = i*256+t holds global (row = s>>3, chunk = (s&7)^(row&7))
    int rowB = t >> 3;
    int colOff = (((t & 7) ^ ((t >> 3) & 7)) << 3);   // shorts
    // reader swizzle: chunk c stored at (c ^ (lr&7))
    int sw0 = ((lq ^ (lr & 7)) << 3);
    int sw1 = (((4 + lq) ^ (lr & 7)) << 3);

    floatx4 acc[4][4];
#pragma unroll
    for (int i = 0; i < 4; i++)
#pragma unroll
        for (int j = 0; j < 4; j++) acc[i][j] = (floatx4)0.f;

    for (int k0 = 0; k0 < K; k0 += 64) {
#pragma unroll
        for (int i = 0; i < 4; i++) {
            int row = i * 32 + rowB;
            GLOAD_LDS16(A + (size_t)(m0 + row) * K + k0 + colOff, &As[(i * 256 + t) * 8]);
            GLOAD_LDS16(Bt + (size_t)(n0 + row) * K + k0 + colOff, &Bs[(i * 256 + t) * 8]);
        }
        __syncthreads();
#pragma unroll
        for (int ksub = 0; ksub < 2; ksub++) {
            int sw = ksub ? sw1 : sw0;
            short8 af[4], bfr[4];
#pragma unroll
            for (int i = 0; i < 4; i++) {
                af[i] = *(const short8*)(&As[(wm + i * 16 + lr) * 64 + sw]);
                bfr[i] = *(const short8*)(&Bs[(wn + i * 16 + lr) * 64 + sw]);
            }
#pragma unroll
            for (int i = 0; i < 4; i++)
#pragma unroll
                for (int j = 0; j < 4; j++)
                    acc[i][j] = __builtin_amdgcn_mfma_f32_16x16x32_bf16(af[i], bfr[j], acc[i][j], 0, 0, 0);
        }
        __syncthreads();
    }

#pragma unroll
    for (int j = 0; j < 4; j++) {
        int gcol = n0 + wn + j * 16 + lr;
        float bv = bias[gcol];
#pragma unroll
        for (int i = 0; i < 4; i++) {
#pragma unroll
            for (int r = 0; r < 4; r++) {
                int grow = m0 + wm + i * 16 + lq * 4 + r;
                float val = acc[i][j][r] + bv;
                if (DO_GELU) val = 0.5f * val * (1.f + erff(val * 0.70710678118654752f));
                val *= scale;
                int orow = DO_REMAP ? win2nat(grow) : grow;
                size_t idx = (size_t)orow * N + gcol;
                if (res) val += res[idx];
                if (OUT_BF16) ((unsigned short*)outv)[idx] = f2bf(val);
                else          ((float*)outv)[idx] = val;
            }
        }
    }
}

extern "C" void kernel_launch(void* const* d_in, const int* in_sizes, int n_in,
                              void* d_out, int out_size, void* d_ws, size_t ws_size,
                              hipStream_t stream) {
    const float* x          = (const float*)d_in[0];
    const float* kv         = (const float*)d_in[1];
    const int*   rel_index  = (const int*)d_in[2];
    const float* g1         = (const float*)d_in[5];
    const float* b1         = (const float*)d_in[6];
    const float* Wqkv       = (const float*)d_in[7];
    const float* bqkv       = (const float*)d_in[8];
    const float* bias_table = (const float*)d_in[9];
    const float* Wproj      = (const float*)d_in[10];
    const float* bproj      = (const float*)d_in[11];
    const float* g2         = (const float*)d_in[12];
    const float* b2         = (const float*)d_in[13];
    const float* Wfc1       = (const float*)d_in[14];
    const float* bfc1       = (const float*)d_in[15];
    const float* Wfc2       = (const float*)d_in[16];
    const float* bfc2       = (const float*)d_in[17];
    float* out = (float*)d_out;

    char* ws = (char*)d_ws;
    unsigned short* wq_t   = (unsigned short*)(ws);
    unsigned short* wp_t   = (unsigned short*)(ws + 294912);
    unsigned short* wfc1_t = (unsigned short*)(ws + 589824);
    unsigned short* wfc2_t = (unsigned short*)(ws + 1769472);
    float*          biasx  = (float*)(ws + 2949120);
    unsigned short* bufA   = (unsigned short*)(ws + 3080192);
    unsigned short* bufB   = (unsigned short*)(ws + 3080192 + 38535168);

    const int M = 50176;
    const float scale = 0.17677669529663687f;
    const int full_mlp = (ws_size >= (size_t)3080192 + 38535168 + 154140672);

    transpose_kernel<<<(384 * 384 + 255) / 256, 256, 0, stream>>>(Wqkv, wq_t, 384, 384, 1152);
    transpose_kernel<<<(384 * 384 + 255) / 256, 256, 0, stream>>>(Wproj, wp_t, 384, 384, 384);
    transpose_kernel<<<(384 * 1536 + 255) / 256, 256, 0, stream>>>(Wfc1, wfc1_t, 384, 1536, 1536);
    transpose_kernel<<<(1536 * 384 + 255) / 256, 256, 0, stream>>>(Wfc2, wfc2_t, 1536, 384, 384);
    bias_expand_kernel<<<(NHEAD * 2401 + 255) / 256, 256, 0, stream>>>(rel_index, bias_table, biasx);

    // LN1 -> windowed (bf16)
    ln_kernel<<<M, 64, 0, stream>>>(x, g1, b1, bufA, 1);
    // q = (hw @ Wq + bq) * scale -> bufB
    gemm_kernel<0, 0, 1><<<dim3(3, 392), 256, 0, stream>>>(bufA, wq_t, bqkv, nullptr, bufB,
                                                           M, 384, 384, scale);
    // attention -> bufA
    attn_kernel<<<16 * NHEAD * 4, 256, 0, stream>>>(bufB, kv, biasx, bufA);
    // proj + window_reverse + residual(x) -> d_out (fp32)
    gemm_kernel<0, 1, 0><<<dim3(3, 392), 256, 0, stream>>>(bufA, wp_t, bproj, x, d_out,
                                                           M, 384, 384, 1.f);
    // LN2
    ln_kernel<<<M, 64, 0, stream>>>(out, g2, b2, bufA, 0);

    if (full_mlp) {
        gemm_kernel<1, 0, 1><<<dim3(12, 392), 256, 0, stream>>>(bufA, wfc1_t, bfc1,
                                                                nullptr, bufB, M, 1536, 384, 1.f);
        gemm_kernel<0, 0, 0><<<dim3(3, 392), 256, 0, stream>>>(bufB, wfc2_t, bfc2,
                                                               out, out, M, 384, 1536, 1.f);
    } else {
        for (int c = 0; c < 4; c++) {
            size_t ro = (size_t)c * 12544;
            gemm_kernel<1, 0, 1><<<dim3(12, 98), 256, 0, stream>>>(bufA + ro * 384, wfc1_t, bfc1,
                                                                   nullptr, bufB, 12544, 1536, 384, 1.f);
            gemm_kernel<0, 0, 0><<<dim3(3, 98), 256, 0, stream>>>(bufB, wfc2_t, bfc2,
                                                                  out + ro * 384, out + ro * 384,
                                                                  12544, 384, 1536, 1.f);
        }
    }
}